// Round 1
// baseline (550.078 us; speedup 1.0000x reference)
//
#include <hip/hip_runtime.h>

#define E_NUM 12000
#define D_DIM 6272
#define H_DIM 256
#define M1 (2 * E_NUM)  // 24000

typedef __attribute__((ext_vector_type(8))) short short8;
typedef __attribute__((ext_vector_type(8))) __bf16 bf16x8;
typedef __attribute__((ext_vector_type(4))) float f32x4;

__device__ __forceinline__ short f2bf(float f) {
  union { float f; unsigned u; } v; v.f = f;
  unsigned r = (v.u + 0x7FFFu + ((v.u >> 16) & 1u)) >> 16;
  return (short)r;
}

__device__ __forceinline__ float silu_f(float x) {
  return x / (1.0f + __expf(-x));
}

__device__ __forceinline__ bf16x8 ld_frag(const short* p) {
  return __builtin_bit_cast(bf16x8, *(const short8*)p);
}

// -------------------- transpose + fp32->bf16 convert --------------------
// src [R][C] fp32 -> dst [C][R] bf16(short). R, C multiples of 32.
__global__ void transpose_cvt(const float* __restrict__ src, short* __restrict__ dst,
                              int R, int C) {
  __shared__ float tile[32][33];
  const int bx = blockIdx.x;  // over C/32
  const int by = blockIdx.y;  // over R/32
  const int t = threadIdx.x;
  const int ci = t & 31;
  const int r0 = t >> 5;  // 0..7
#pragma unroll
  for (int i = 0; i < 4; ++i) {
    int ri = r0 + i * 8;
    tile[ri][ci] = src[(size_t)(by * 32 + ri) * C + bx * 32 + ci];
  }
  __syncthreads();
#pragma unroll
  for (int i = 0; i < 4; ++i) {
    int orow = r0 + i * 8;  // row within dst tile
    dst[(size_t)(bx * 32 + orow) * R + by * 32 + ci] = f2bf(tile[ci][orow]);
  }
}

// -------------------- GEMM1: h = silu(x @ W1 + b1) * gate, bf16 out --------------------
// x = concat(node_embed, ori) [24000][6272] fp32 (converted on the fly)
// W1T [256][6272] bf16. Output hg [24000][256] bf16.
__launch_bounds__(256, 2)
__global__ void gemm1_kernel(const float* __restrict__ node_embed,
                             const float* __restrict__ ori,
                             const float* __restrict__ x_edge_c,
                             const short* __restrict__ W1T,
                             const float* __restrict__ b1,
                             short* __restrict__ hg) {
  __shared__ short Als[64][40];   // 64 rows x 32 k, padded to 40
  __shared__ short Bls[256][40];  // 256 cols x 32 k, padded to 40

  const int t = threadIdx.x;
  const int wave = t >> 6;
  const int lane = t & 63;
  const int l15 = lane & 15;
  const int lq = lane >> 4;  // 0..3
  const int m_base = blockIdx.x * 64;

  // A staging: thread t stages 8 fp32 -> 8 bf16 at row ar, k-offset ak
  const int ar = t >> 2;        // 0..63
  const int ak = (t & 3) * 8;   // 0,8,16,24
  const int gm = m_base + ar;
  const float* arow = (gm < E_NUM) ? (node_embed + (size_t)gm * D_DIM)
                                   : (ori + (size_t)(gm - E_NUM) * D_DIM);
  // B staging: thread t stages W1T row t (32 bf16 per k-step)
  const short* brow = W1T + (size_t)t * D_DIM;

  f32x4 acc[4][4];
#pragma unroll
  for (int m = 0; m < 4; ++m)
#pragma unroll
    for (int n = 0; n < 4; ++n) acc[m][n] = (f32x4){0.f, 0.f, 0.f, 0.f};

  for (int k0 = 0; k0 < D_DIM; k0 += 32) {
    f32x4 a0 = *(const f32x4*)(arow + k0 + ak);
    f32x4 a1 = *(const f32x4*)(arow + k0 + ak + 4);
    short8 apack;
#pragma unroll
    for (int j = 0; j < 4; ++j) {
      apack[j] = f2bf(a0[j]);
      apack[j + 4] = f2bf(a1[j]);
    }
    *(short8*)&Als[ar][ak] = apack;
#pragma unroll
    for (int j = 0; j < 4; ++j) {
      *(short8*)&Bls[t][j * 8] = *(const short8*)(brow + k0 + j * 8);
    }
    __syncthreads();

    bf16x8 af[4], bf[4];
#pragma unroll
    for (int m = 0; m < 4; ++m) af[m] = ld_frag(&Als[m * 16 + l15][lq * 8]);
#pragma unroll
    for (int n = 0; n < 4; ++n) bf[n] = ld_frag(&Bls[wave * 64 + n * 16 + l15][lq * 8]);
#pragma unroll
    for (int m = 0; m < 4; ++m)
#pragma unroll
      for (int n = 0; n < 4; ++n)
        acc[m][n] = __builtin_amdgcn_mfma_f32_16x16x32_bf16(af[m], bf[n], acc[m][n], 0, 0, 0);
    __syncthreads();
  }

  // epilogue: bias + silu + gate, store bf16
#pragma unroll
  for (int n = 0; n < 4; ++n) {
    const int col = wave * 64 + n * 16 + l15;
    const float b1v = b1[col];
#pragma unroll
    for (int m = 0; m < 4; ++m) {
#pragma unroll
      for (int i = 0; i < 4; ++i) {
        const int row = m * 16 + lq * 4 + i;
        const int gmr = m_base + row;
        const int e = (gmr < E_NUM) ? gmr : gmr - E_NUM;
        float v = acc[m][n][i] + b1v;
        v = silu_f(v) * x_edge_c[(size_t)e * H_DIM + col];
        hg[(size_t)gmr * H_DIM + col] = f2bf(v);
      }
    }
  }
}

// -------------------- GEMM2: out[e] = silu(hg[e]@W2+b2) + silu(hg[e+E]@W2+b2) ------------
// hg [24000][256] bf16, W2T [6272][256] bf16, out [12000][6272] fp32
__launch_bounds__(256, 2)
__global__ void gemm2_kernel(const short* __restrict__ hg,
                             const short* __restrict__ W2T,
                             const float* __restrict__ b2,
                             float* __restrict__ out) {
  __shared__ short Als[2][64][40];  // [half][row][k] padded
  __shared__ short Bls[128][40];    // [col_d][k] padded

  const int t = threadIdx.x;
  const int wave = t >> 6;
  const int lane = t & 63;
  const int l15 = lane & 15;
  const int lq = lane >> 4;
  const int wr = wave >> 1;  // row half of wave grid (2x2)
  const int wc = wave & 1;   // col half

  const int d0 = blockIdx.x * 128;
  const int e0 = blockIdx.y * 64;

  // staging: thread t stages 16 bf16 (two 16B writes)
  const int srow = t >> 1;       // 0..127
  const int sk = (t & 1) * 16;   // 0 or 16
  const int half = srow >> 6;    // 0/1 (for A)
  const int r = srow & 63;
  int ge = e0 + r;
  if (ge >= E_NUM) ge = E_NUM - 1;  // clamp: garbage rows never stored
  const short* a_src = hg + (size_t)(ge + half * E_NUM) * H_DIM + sk;
  const short* b_src = W2T + (size_t)(d0 + srow) * H_DIM + sk;

  f32x4 acc[2][2][4];
#pragma unroll
  for (int h = 0; h < 2; ++h)
#pragma unroll
    for (int m = 0; m < 2; ++m)
#pragma unroll
      for (int n = 0; n < 4; ++n) acc[h][m][n] = (f32x4){0.f, 0.f, 0.f, 0.f};

  for (int k0 = 0; k0 < H_DIM; k0 += 32) {
    *(short8*)&Als[half][r][sk] = *(const short8*)(a_src + k0);
    *(short8*)&Als[half][r][sk + 8] = *(const short8*)(a_src + k0 + 8);
    *(short8*)&Bls[srow][sk] = *(const short8*)(b_src + k0);
    *(short8*)&Bls[srow][sk + 8] = *(const short8*)(b_src + k0 + 8);
    __syncthreads();

    bf16x8 af[2][2], bfr[4];
#pragma unroll
    for (int h = 0; h < 2; ++h)
#pragma unroll
      for (int m = 0; m < 2; ++m)
        af[h][m] = ld_frag(&Als[h][wr * 32 + m * 16 + l15][lq * 8]);
#pragma unroll
    for (int n = 0; n < 4; ++n)
      bfr[n] = ld_frag(&Bls[wc * 64 + n * 16 + l15][lq * 8]);
#pragma unroll
    for (int h = 0; h < 2; ++h)
#pragma unroll
      for (int m = 0; m < 2; ++m)
#pragma unroll
        for (int n = 0; n < 4; ++n)
          acc[h][m][n] =
              __builtin_amdgcn_mfma_f32_16x16x32_bf16(af[h][m], bfr[n], acc[h][m][n], 0, 0, 0);
    __syncthreads();
  }

#pragma unroll
  for (int n = 0; n < 4; ++n) {
    const int cold = d0 + wc * 64 + n * 16 + l15;
    const float b2v = b2[cold];
#pragma unroll
    for (int m = 0; m < 2; ++m) {
#pragma unroll
      for (int i = 0; i < 4; ++i) {
        const int e = e0 + wr * 32 + m * 16 + lq * 4 + i;
        if (e < E_NUM) {
          float v0 = silu_f(acc[0][m][n][i] + b2v);
          float v1 = silu_f(acc[1][m][n][i] + b2v);
          out[(size_t)e * D_DIM + cold] = v0 + v1;
        }
      }
    }
  }
}

extern "C" void kernel_launch(void* const* d_in, const int* in_sizes, int n_in,
                              void* d_out, int out_size, void* d_ws, size_t ws_size,
                              hipStream_t stream) {
  const float* node_embed = (const float*)d_in[0];
  const float* x_edge_c = (const float*)d_in[1];
  const float* ori = (const float*)d_in[2];
  const float* W1 = (const float*)d_in[3];
  const float* b1 = (const float*)d_in[4];
  const float* W2 = (const float*)d_in[5];
  const float* b2 = (const float*)d_in[6];
  float* out_p = (float*)d_out;

  char* ws = (char*)d_ws;
  // W1T bf16 [256][6272]  : 3,211,264 B
  // W2T bf16 [6272][256]  : 3,211,264 B
  // hg  bf16 [24000][256] : 12,288,000 B  (total 18,710,528 B)
  short* W1T = (short*)ws;
  short* W2T = (short*)(ws + 3211264);
  short* hg = (short*)(ws + 2 * 3211264);

  // W1 [6272][256] -> W1T [256][6272]
  transpose_cvt<<<dim3(H_DIM / 32, D_DIM / 32), 256, 0, stream>>>(W1, W1T, D_DIM, H_DIM);
  // W2 [256][6272] -> W2T [6272][256]
  transpose_cvt<<<dim3(D_DIM / 32, H_DIM / 32), 256, 0, stream>>>(W2, W2T, H_DIM, D_DIM);

  gemm1_kernel<<<dim3(M1 / 64), 256, 0, stream>>>(node_embed, ori, x_edge_c, W1T, b1, hg);

  gemm2_kernel<<<dim3(D_DIM / 128, (E_NUM + 63) / 64), 256, 0, stream>>>(hg, W2T, b2, out_p);
}

// Round 2
// 546.729 us; speedup vs baseline: 1.0061x; 1.0061x over previous
//
#include <hip/hip_runtime.h>

#define E_NUM 12000
#define D_DIM 6272
#define H_DIM 256
#define M1 (2 * E_NUM)  // 24000

typedef __attribute__((ext_vector_type(4))) short short4v;
typedef __attribute__((ext_vector_type(8))) short short8;
typedef __attribute__((ext_vector_type(8))) __bf16 bf16x8;
typedef __attribute__((ext_vector_type(4))) float f32x4;

__device__ __forceinline__ short f2bf(float f) {
  union { float f; unsigned u; } v; v.f = f;
  unsigned r = (v.u + 0x7FFFu + ((v.u >> 16) & 1u)) >> 16;
  return (short)r;
}

__device__ __forceinline__ float silu_f(float x) {
  return x / (1.0f + __expf(-x));
}

__device__ __forceinline__ bf16x8 ld_frag(const short* p) {
  return __builtin_bit_cast(bf16x8, *(const short8*)p);
}

// async global->LDS, 16B per lane; lds base wave-uniform, global addr per-lane
__device__ __forceinline__ void gll16(const void* g, void* l) {
  __builtin_amdgcn_global_load_lds(
      (const __attribute__((address_space(1))) void*)g,
      (__attribute__((address_space(3))) void*)l, 16, 0, 0);
}

// -------------------- transpose + fp32->bf16 convert --------------------
__global__ void transpose_cvt(const float* __restrict__ src, short* __restrict__ dst,
                              int R, int C) {
  __shared__ float tile[32][33];
  const int bx = blockIdx.x;  // over C/32
  const int by = blockIdx.y;  // over R/32
  const int t = threadIdx.x;
  const int ci = t & 31;
  const int r0 = t >> 5;
#pragma unroll
  for (int i = 0; i < 4; ++i) {
    int ri = r0 + i * 8;
    tile[ri][ci] = src[(size_t)(by * 32 + ri) * C + bx * 32 + ci];
  }
  __syncthreads();
#pragma unroll
  for (int i = 0; i < 4; ++i) {
    int orow = r0 + i * 8;
    dst[(size_t)(bx * 32 + orow) * R + by * 32 + ci] = f2bf(tile[ci][orow]);
  }
}

// -------------------- GEMM1 v2: BM=32, BK=32, dbuf + gll(B) + reg-staged A -----------
// x = concat(node_embed, ori) [24000][6272] fp32, W1T [256][6272] bf16 (in ws)
// hg [24000][256] bf16 out
#define G1_KIT (D_DIM / 32)  // 196
__launch_bounds__(256, 4)
__global__ void gemm1_kernel(const float* __restrict__ node_embed,
                             const float* __restrict__ ori,
                             const float* __restrict__ x_edge_c,
                             const short* __restrict__ W1T,
                             const float* __restrict__ b1,
                             short* __restrict__ hg) {
  // B: [buf][256 rows][32 k-shorts] linear (64B/row), chunk-XOR-swizzled via source
  // A: [buf][32 rows][40 shorts] padded
  __shared__ __align__(16) short Bls[2][256 * 32];
  __shared__ __align__(16) short Als[2][32 * 40];

  const int t = threadIdx.x;
  const int wave = t >> 6;
  const int lane = t & 63;
  const int l15 = lane & 15;
  const int lq = lane >> 4;
  const int m_base = blockIdx.x * 32;

  // ---- A staging coords: thread t loads 4 fp32 of row (t>>3), float-offset (t&7)*4
  const int ar = t >> 3;
  const int ac = (t & 7) * 4;
  const int gm = m_base + ar;
  const float* arow = (gm < E_NUM) ? (node_embed + (size_t)gm * D_DIM + ac)
                                   : (ori + (size_t)(gm - E_NUM) * D_DIM + ac);

  // ---- B gll coords: wave call c stages rows [(wave*4+c)*16, +16), this lane:
  // row = base + (lane>>2), stored pos p = lane&3, data chunk = p ^ ((lane>>3)&3)
  const short* bsrc[4];
#pragma unroll
  for (int c = 0; c < 4; ++c) {
    const int row = (wave * 4 + c) * 16 + (lane >> 2);
    const int dc = (lane & 3) ^ ((lane >> 3) & 3);
    bsrc[c] = W1T + (size_t)row * D_DIM + dc * 8;
  }

  // ---- fragment-read offsets
  // B read: data chunk lq of row r is stored at p = lq ^ ((r>>1)&3); r>>1&3 == (l15>>1)&3
  const int bpofs = (lq ^ ((l15 >> 1) & 3)) * 8;
  const int aofs = l15 * 40 + lq * 8;

  f32x4 acc[2][4];
#pragma unroll
  for (int m = 0; m < 2; ++m)
#pragma unroll
    for (int n = 0; n < 4; ++n) acc[m][n] = (f32x4){0.f, 0.f, 0.f, 0.f};

  // ---- prologue: stage tile 0 into buf 0
  {
    f32x4 a0 = *(const f32x4*)(arow);
#pragma unroll
    for (int c = 0; c < 4; ++c) gll16(bsrc[c], &Bls[0][(wave * 4 + c) * 512]);
    short4v ap;
#pragma unroll
    for (int j = 0; j < 4; ++j) ap[j] = f2bf(a0[j]);
    *(short4v*)&Als[0][ar * 40 + ac] = ap;
  }
  __syncthreads();

  int cur = 0;
  for (int it = 0; it < G1_KIT; ++it) {
    const int nxt = cur ^ 1;
    const bool pf = (it + 1 < G1_KIT);
    f32x4 areg;
    if (pf) {
      const int k0 = (it + 1) * 32;
      areg = *(const f32x4*)(arow + k0);  // issued first: cvt waits vmcnt(4), glls fly
#pragma unroll
      for (int c = 0; c < 4; ++c) gll16(bsrc[c] + k0, &Bls[nxt][(wave * 4 + c) * 512]);
    }

    // compute current tile
    bf16x8 af[2], bfv[4];
#pragma unroll
    for (int m = 0; m < 2; ++m) af[m] = ld_frag(&Als[cur][m * 16 * 40 + aofs]);
#pragma unroll
    for (int n = 0; n < 4; ++n)
      bfv[n] = ld_frag(&Bls[cur][(wave * 64 + n * 16 + l15) * 32 + bpofs]);
#pragma unroll
    for (int m = 0; m < 2; ++m)
#pragma unroll
      for (int n = 0; n < 4; ++n)
        acc[m][n] = __builtin_amdgcn_mfma_f32_16x16x32_bf16(af[m], bfv[n], acc[m][n], 0, 0, 0);

    if (pf) {
      short4v ap;
#pragma unroll
      for (int j = 0; j < 4; ++j) ap[j] = f2bf(areg[j]);
      *(short4v*)&Als[nxt][ar * 40 + ac] = ap;
    }
    __syncthreads();  // drains vmcnt (gll complete) + lgkm; nxt fully staged
    cur = nxt;
  }

  // ---- epilogue: bias + silu + gate -> bf16
#pragma unroll
  for (int n = 0; n < 4; ++n) {
    const int col = wave * 64 + n * 16 + l15;
    const float b1v = b1[col];
#pragma unroll
    for (int m = 0; m < 2; ++m) {
#pragma unroll
      for (int i = 0; i < 4; ++i) {
        const int row = m * 16 + lq * 4 + i;
        const int gmr = m_base + row;
        const int e = (gmr < E_NUM) ? gmr : gmr - E_NUM;
        float v = acc[m][n][i] + b1v;
        v = silu_f(v) * x_edge_c[(size_t)e * H_DIM + col];
        hg[(size_t)gmr * H_DIM + col] = f2bf(v);
      }
    }
  }
}

// -------------------- GEMM2: out[e] = silu(hg[e]@W2+b2) + silu(hg[e+E]@W2+b2) ------------
__launch_bounds__(256, 2)
__global__ void gemm2_kernel(const short* __restrict__ hg,
                             const short* __restrict__ W2T,
                             const float* __restrict__ b2,
                             float* __restrict__ out) {
  __shared__ short Als[2][64][40];
  __shared__ short Bls[128][40];

  const int t = threadIdx.x;
  const int wave = t >> 6;
  const int lane = t & 63;
  const int l15 = lane & 15;
  const int lq = lane >> 4;
  const int wr = wave >> 1;
  const int wc = wave & 1;

  const int d0 = blockIdx.x * 128;
  const int e0 = blockIdx.y * 64;

  const int srow = t >> 1;
  const int sk = (t & 1) * 16;
  const int half = srow >> 6;
  const int r = srow & 63;
  int ge = e0 + r;
  if (ge >= E_NUM) ge = E_NUM - 1;
  const short* a_src = hg + (size_t)(ge + half * E_NUM) * H_DIM + sk;
  const short* b_src = W2T + (size_t)(d0 + srow) * H_DIM + sk;

  f32x4 acc[2][2][4];
#pragma unroll
  for (int h = 0; h < 2; ++h)
#pragma unroll
    for (int m = 0; m < 2; ++m)
#pragma unroll
      for (int n = 0; n < 4; ++n) acc[h][m][n] = (f32x4){0.f, 0.f, 0.f, 0.f};

  for (int k0 = 0; k0 < H_DIM; k0 += 32) {
    *(short8*)&Als[half][r][sk] = *(const short8*)(a_src + k0);
    *(short8*)&Als[half][r][sk + 8] = *(const short8*)(a_src + k0 + 8);
    *(short8*)&Bls[srow][sk] = *(const short8*)(b_src + k0);
    *(short8*)&Bls[srow][sk + 8] = *(const short8*)(b_src + k0 + 8);
    __syncthreads();

    bf16x8 af[2][2], bfr[4];
#pragma unroll
    for (int h = 0; h < 2; ++h)
#pragma unroll
      for (int m = 0; m < 2; ++m)
        af[h][m] = ld_frag(&Als[h][wr * 32 + m * 16 + l15][lq * 8]);
#pragma unroll
    for (int n = 0; n < 4; ++n)
      bfr[n] = ld_frag(&Bls[wc * 64 + n * 16 + l15][lq * 8]);
#pragma unroll
    for (int h = 0; h < 2; ++h)
#pragma unroll
      for (int m = 0; m < 2; ++m)
#pragma unroll
        for (int n = 0; n < 4; ++n)
          acc[h][m][n] =
              __builtin_amdgcn_mfma_f32_16x16x32_bf16(af[h][m], bfr[n], acc[h][m][n], 0, 0, 0);
    __syncthreads();
  }

#pragma unroll
  for (int n = 0; n < 4; ++n) {
    const int cold = d0 + wc * 64 + n * 16 + l15;
    const float b2v = b2[cold];
#pragma unroll
    for (int m = 0; m < 2; ++m) {
#pragma unroll
      for (int i = 0; i < 4; ++i) {
        const int e = e0 + wr * 32 + m * 16 + lq * 4 + i;
        if (e < E_NUM) {
          float v0 = silu_f(acc[0][m][n][i] + b2v);
          float v1 = silu_f(acc[1][m][n][i] + b2v);
          out[(size_t)e * D_DIM + cold] = v0 + v1;
        }
      }
    }
  }
}

extern "C" void kernel_launch(void* const* d_in, const int* in_sizes, int n_in,
                              void* d_out, int out_size, void* d_ws, size_t ws_size,
                              hipStream_t stream) {
  const float* node_embed = (const float*)d_in[0];
  const float* x_edge_c = (const float*)d_in[1];
  const float* ori = (const float*)d_in[2];
  const float* W1 = (const float*)d_in[3];
  const float* b1 = (const float*)d_in[4];
  const float* W2 = (const float*)d_in[5];
  const float* b2 = (const float*)d_in[6];
  float* out_p = (float*)d_out;

  char* ws = (char*)d_ws;
  short* W1T = (short*)ws;
  short* W2T = (short*)(ws + 3211264);
  short* hg = (short*)(ws + 2 * 3211264);

  transpose_cvt<<<dim3(H_DIM / 32, D_DIM / 32), 256, 0, stream>>>(W1, W1T, D_DIM, H_DIM);
  transpose_cvt<<<dim3(D_DIM / 32, H_DIM / 32), 256, 0, stream>>>(W2, W2T, H_DIM, D_DIM);

  gemm1_kernel<<<dim3(M1 / 32), 256, 0, stream>>>(node_embed, ori, x_edge_c, W1T, b1, hg);

  gemm2_kernel<<<dim3(D_DIM / 128, (E_NUM + 63) / 64), 256, 0, stream>>>(hg, W2T, b2, out_p);
}